// Round 8
// baseline (203.898 us; speedup 1.0000x reference)
//
#include <hip/hip_runtime.h>

#define H 512
#define W 512
#define RH 508
#define RW 508
#define OH 510
#define OW 510
#define CHUNK 32          // output rows per block
#define NCHUNK 16         // 16*32 = 512 >= 510
#define ITERS (CHUNK/2)   // 2 rows per iteration
#define REPS 3            // DIAGNOSTIC: repeat identical work to surface this
                          // dispatch into the duration-sorted rocprof top-5

// R5 rolling-row fused morphology, unchanged except the REPS diagnostic loop.

__global__ __launch_bounds__(256) void morph2d_roll(
    const float* __restrict__ x,      // (4,512,512)
    const float* __restrict__ wgt,    // (16,3,3) binary
    float* __restrict__ out)          // (4,64,510,510)
{
    __shared__ float2 dering[8][512];   // 32 KB ring of (dil,ero) rows

    const int tid   = threadIdx.x;
    const int bg    = blockIdx.x & 63;          // b*16+g
    const int chunk = blockIdx.x >> 6;          // 0..15
    const int b     = bg >> 4;
    const int g     = bg & 15;
    const int L     = chunk * CHUNK;

    const int lane  = tid & 127;      // column group: cols 4*lane..4*lane+3
    const int rsel  = tid >> 7;       // row of the pair (uniform per wave)
    const int c4    = lane * 4;       // 0..508

    // uniform binary weight mask
    int wm = 0;
#pragma unroll
    for (int t = 0; t < 9; ++t) wm |= (wgt[g * 9 + t] > 0.5f) ? (1 << t) : 0;
    wm = __builtin_amdgcn_readfirstlane(wm);

    const float*  xb    = x + (size_t)b * (H * W);
    const size_t  plane = (size_t)OH * OW;
    float*        outbg = out + (size_t)bg * 4 * plane;

    auto compute_de = [&](int deR, float dd[4], float ee[4]) {
        float xr[3][8];
#pragma unroll
        for (int i = 0; i < 3; ++i) {
            const float* p = xb + (size_t)(deR + i) * W + c4;
            *(float4*)&xr[i][0] = *(const float4*)p;
            *(float4*)&xr[i][4] = *(const float4*)(p + 4);
        }
#pragma unroll
        for (int p = 0; p < 4; ++p) { dd[p] = 0.f; ee[p] = INFINITY; }
#pragma unroll
        for (int T = 0; T < 9; ++T) {
            const int ti = T / 3, tj = T % 3;
            if (wm & (1 << T)) {
#pragma unroll
                for (int p = 0; p < 4; ++p) {
                    float xv = xr[ti][p + tj];
                    dd[p] = fmaxf(dd[p], fabsf(xv));         // |x*1|
                    ee[p] = fminf(ee[p], fabsf(xv + 1.0f));  // |x+1|
                }
            } else {
#pragma unroll
                for (int p = 0; p < 4; ++p)
                    ee[p] = fminf(ee[p], fabsf(xr[ti][p + tj]));  // |x+0|
            }
        }
    };

    auto store_row = [&](int ch, int row, const float v[4]) {
        float* p = outbg + (size_t)ch * plane + (size_t)row * OW + c4;
        if (lane < 127) {
            __builtin_memcpy(p, v, 16);
        } else {
            float2 z = make_float2(v[0], v[1]);
            __builtin_memcpy(p, &z, 8);
        }
    };

    auto ring_write = [&](int row, const float dd[4], const float ee[4]) {
        float2* rp = &dering[row & 7][c4];
        float4 w0, w1;
        ((float2*)&w0)[0] = make_float2(dd[0], ee[0]);
        ((float2*)&w0)[1] = make_float2(dd[1], ee[1]);
        ((float2*)&w1)[0] = make_float2(dd[2], ee[2]);
        ((float2*)&w1)[1] = make_float2(dd[3], ee[3]);
        *(float4*)rp       = w0;
        *(float4*)(rp + 2) = w1;
    };

    for (int rep = 0; rep < REPS; ++rep) {
        // ---- prologue: de rows L, L+1 into ring (chunk 0 also stores them) ----
        {
            const int deR = L + rsel;
            float dd[4] = {0, 0, 0, 0}, ee[4] = {0, 0, 0, 0};
            if (lane < 127 && deR < RH) compute_de(deR, dd, ee);
            ring_write(deR, dd, ee);
            if (chunk == 0) { store_row(0, deR, dd); store_row(1, deR, ee); }
        }

#pragma unroll 2
        for (int i = 0; i < ITERS; ++i) {
            // ---- de phase: rows L+2i+2, L+2i+3 ----
            const int deR = L + 2 * i + 2 + rsel;
            float dd[4] = {0, 0, 0, 0}, ee[4] = {0, 0, 0, 0};
            if (lane < 127 && deR < RH) compute_de(deR, dd, ee);
            if (deR < OH) {
                ring_write(deR, dd, ee);          // rows 508/509 written as zeros
                store_row(0, deR, dd);
                store_row(1, deR, ee);
            }
            __syncthreads();

            // ---- oc phase: rows L+2i, L+2i+1 ----
            const int ocR = L + 2 * i + rsel;
            float oo[4] = {0, 0, 0, 0}, cc[4] = {0, 0, 0, 0};
            if (lane < 127 && ocR < RH) {
                float2 win[3][6];
#pragma unroll
                for (int k = 0; k < 3; ++k) {
                    const float2* rp = &dering[(ocR + k) & 7][c4];
                    *(float4*)&win[k][0] = *(const float4*)rp;
                    *(float4*)&win[k][2] = *(const float4*)(rp + 2);
                    *(float4*)&win[k][4] = *(const float4*)(rp + 4);
                }
                float m1[4] = {INFINITY, INFINITY, INFINITY, INFINITY};
                float m0[4] = {INFINITY, INFINITY, INFINITY, INFINITY};
#pragma unroll
                for (int T = 0; T < 9; ++T) {
                    const int ti = T / 3, tj = T % 3;
                    if (wm & (1 << T)) {
#pragma unroll
                        for (int p = 0; p < 4; ++p) {
                            oo[p] = fmaxf(oo[p], win[ti][p + tj].y);
                            m1[p] = fminf(m1[p], win[ti][p + tj].x);
                        }
                    } else {
#pragma unroll
                        for (int p = 0; p < 4; ++p)
                            m0[p] = fminf(m0[p], win[ti][p + tj].x);
                    }
                }
#pragma unroll
                for (int p = 0; p < 4; ++p) cc[p] = fminf(m1[p] + 1.0f, m0[p]);
            }
            if (ocR < OH) { store_row(2, ocR, oo); store_row(3, ocR, cc); }
        }
        __syncthreads();   // isolate reps: next prologue's ring slots overlap last oc reads
    }
}

extern "C" void kernel_launch(void* const* d_in, const int* in_sizes, int n_in,
                              void* d_out, int out_size, void* d_ws, size_t ws_size,
                              hipStream_t stream) {
    const float* x = (const float*)d_in[0];   // (4,1,512,512) f32
    const float* w = (const float*)d_in[1];   // (16,1,3,3)  f32
    float* out = (float*)d_out;               // (4,64,510,510) f32
    dim3 grid(64 * NCHUNK);                   // 1024 blocks: (bg, chunk)
    morph2d_roll<<<grid, 256, 0, stream>>>(x, w, out);
}

// Round 9
// 78.205 us; speedup vs baseline: 2.6072x; 2.6072x over previous
//
#include <hip/hip_runtime.h>

#define H 512
#define W 512
#define RH 508
#define RW 508
#define OH 510
#define OW 510
#define CHUNK 32          // output rows per block
#define NCHUNK 16         // 16*32 = 512 >= 510
#define ITERS (CHUNK/2)   // 2 rows per iteration
#define RP 520            // ring row pitch (512 + pad so halo reads stay in-bounds)

// Rolling-row fused morphology (R5 schedule), with SEPARATE d/e LDS rings:
// lane stride 16 B (dense, bank-conflict-free) instead of the 32 B float2
// interleave (16-way conflict, measured 7.4e6 conflict-cycles/rep in R8),
// and no interleave-packing movs.

__global__ __launch_bounds__(256) void morph2d_roll(
    const float* __restrict__ x,      // (4,512,512)
    const float* __restrict__ wgt,    // (16,3,3) binary
    float* __restrict__ out)          // (4,64,510,510)
{
    __shared__ float d_ring[8][RP];   // 16.25 KB
    __shared__ float e_ring[8][RP];   // 16.25 KB

    const int tid   = threadIdx.x;
    const int bg    = blockIdx.x & 63;          // b*16+g
    const int chunk = blockIdx.x >> 6;          // 0..15
    const int b     = bg >> 4;
    const int g     = bg & 15;
    const int L     = chunk * CHUNK;

    const int lane  = tid & 127;      // column group: cols 4*lane..4*lane+3
    const int rsel  = tid >> 7;       // row of the pair (uniform per wave)
    const int c4    = lane * 4;       // 0..508

    // uniform binary weight mask
    int wm = 0;
#pragma unroll
    for (int t = 0; t < 9; ++t) wm |= (wgt[g * 9 + t] > 0.5f) ? (1 << t) : 0;
    wm = __builtin_amdgcn_readfirstlane(wm);

    const float*  xb    = x + (size_t)b * (H * W);
    const size_t  plane = (size_t)OH * OW;
    float*        outbg = out + (size_t)bg * 4 * plane;

    auto compute_de = [&](int deR, float dd[4], float ee[4]) {
        float xr[3][8];
#pragma unroll
        for (int i = 0; i < 3; ++i) {
            const float* p = xb + (size_t)(deR + i) * W + c4;
            *(float4*)&xr[i][0] = *(const float4*)p;
            *(float4*)&xr[i][4] = *(const float4*)(p + 4);
        }
#pragma unroll
        for (int p = 0; p < 4; ++p) { dd[p] = 0.f; ee[p] = INFINITY; }
#pragma unroll
        for (int T = 0; T < 9; ++T) {
            const int ti = T / 3, tj = T % 3;
            if (wm & (1 << T)) {
#pragma unroll
                for (int p = 0; p < 4; ++p) {
                    float xv = xr[ti][p + tj];
                    dd[p] = fmaxf(dd[p], fabsf(xv));         // |x*1|
                    ee[p] = fminf(ee[p], fabsf(xv + 1.0f));  // |x+1|
                }
            } else {
#pragma unroll
                for (int p = 0; p < 4; ++p)
                    ee[p] = fminf(ee[p], fabsf(xr[ti][p + tj]));  // |x+0|
            }
        }
    };

    auto store_row = [&](int ch, int row, const float v[4]) {
        float* p = outbg + (size_t)ch * plane + (size_t)row * OW + c4;
        if (lane < 127) {
            __builtin_memcpy(p, v, 16);
        } else {
            float2 z = make_float2(v[0], v[1]);
            __builtin_memcpy(p, &z, 8);
        }
    };

    auto ring_write = [&](int row, const float dd[4], const float ee[4]) {
        const int slot = row & 7;
        *(float4*)&d_ring[slot][c4] = make_float4(dd[0], dd[1], dd[2], dd[3]);
        *(float4*)&e_ring[slot][c4] = make_float4(ee[0], ee[1], ee[2], ee[3]);
    };

    // ---- prologue: de rows L, L+1 into ring (chunk 0 also stores them) ----
    {
        const int deR = L + rsel;
        float dd[4] = {0, 0, 0, 0}, ee[4] = {0, 0, 0, 0};
        if (lane < 127 && deR < RH) compute_de(deR, dd, ee);
        ring_write(deR, dd, ee);
        if (chunk == 0) { store_row(0, deR, dd); store_row(1, deR, ee); }
    }
    // visibility of prologue ring writes is covered by iteration 0's barrier

#pragma unroll 2
    for (int i = 0; i < ITERS; ++i) {
        // ---- de phase: rows L+2i+2, L+2i+3 ----
        const int deR = L + 2 * i + 2 + rsel;
        float dd[4] = {0, 0, 0, 0}, ee[4] = {0, 0, 0, 0};
        if (lane < 127 && deR < RH) compute_de(deR, dd, ee);
        if (deR < OH) {
            ring_write(deR, dd, ee);          // rows 508/509 written as zeros
            store_row(0, deR, dd);
            store_row(1, deR, ee);
        }
        __syncthreads();

        // ---- oc phase: rows L+2i, L+2i+1 ----
        const int ocR = L + 2 * i + rsel;
        float oo[4] = {0, 0, 0, 0}, cc[4] = {0, 0, 0, 0};
        if (lane < 127 && ocR < RH) {
            float dwin[3][6], ewin[3][6];
#pragma unroll
            for (int k = 0; k < 3; ++k) {
                const int slot = (ocR + k) & 7;
                *(float4*)&dwin[k][0] = *(const float4*)&d_ring[slot][c4];
                *(float2*)&dwin[k][4] = *(const float2*)&d_ring[slot][c4 + 4];
                *(float4*)&ewin[k][0] = *(const float4*)&e_ring[slot][c4];
                *(float2*)&ewin[k][4] = *(const float2*)&e_ring[slot][c4 + 4];
            }
            float m1[4] = {INFINITY, INFINITY, INFINITY, INFINITY};
            float m0[4] = {INFINITY, INFINITY, INFINITY, INFINITY};
#pragma unroll
            for (int T = 0; T < 9; ++T) {
                const int ti = T / 3, tj = T % 3;
                if (wm & (1 << T)) {
#pragma unroll
                    for (int p = 0; p < 4; ++p) {
                        oo[p] = fmaxf(oo[p], ewin[ti][p + tj]);  // ero>=0
                        m1[p] = fminf(m1[p], dwin[ti][p + tj]);  // min dil, w=1
                    }
                } else {
#pragma unroll
                    for (int p = 0; p < 4; ++p)
                        m0[p] = fminf(m0[p], dwin[ti][p + tj]);  // min dil, w=0
                }
            }
#pragma unroll
            for (int p = 0; p < 4; ++p) cc[p] = fminf(m1[p] + 1.0f, m0[p]);
        }
        if (ocR < OH) { store_row(2, ocR, oo); store_row(3, ocR, cc); }
        // no second barrier: next iter's ring-write slots (2i+4,2i+5)&7 are
        // disjoint from this oc read set (2i..2i+3)&7; slot reuse is >=2
        // barriers away.
    }
}

extern "C" void kernel_launch(void* const* d_in, const int* in_sizes, int n_in,
                              void* d_out, int out_size, void* d_ws, size_t ws_size,
                              hipStream_t stream) {
    const float* x = (const float*)d_in[0];   // (4,1,512,512) f32
    const float* w = (const float*)d_in[1];   // (16,1,3,3)  f32
    float* out = (float*)d_out;               // (4,64,510,510) f32
    dim3 grid(64 * NCHUNK);                   // 1024 blocks: (bg, chunk)
    morph2d_roll<<<grid, 256, 0, stream>>>(x, w, out);
}